// Round 5
// baseline (516.902 us; speedup 1.0000x reference)
//
#include <hip/hip_runtime.h>

// TimeGraphNet [64,1024,1200] f32 -> softmax [64,3].
//
// R4: persistent blocks + register-prefetch pipeline.
//  K1: 2048 blocks x 256 threads; block owns 32 consecutive rows = 8
//      generations of 4 rows. Per generation: regs->LDS, barrier, issue
//      NEXT generation's global loads into regs (in flight across the
//      barrier + compute), compute (1 row/wave, lane=window,
//      ds_read_b128), wave-shuffle tail, barrier. Writes feat[row].
//  K2: classifier, 64 blocks: 3x dot-1024 + softmax (exact since R0).
//
// Per-row math (verified exact R0-R3):
//  y1[j] = relu(b1 + sum_{k=0..9} w1[k]*x[8j-1+k]), j=0..149, zero pad
//  p1[m] = max(y1[5m..5m+4])                                   (30 vals)
//  y2[j] = relu(b2 + sum_{k=0..2} w2[k]*p1[3j+k]), j=0..9
//  p2 = {max(y2[0],y2[1]), max(y2[2..4]), max(y2[5..7]), max(y2[8],y2[9])}
//  feat = relu(b3 + dot(w3, p2))

#define NROWS 65536
#define ROWS_PER_GEN 4
#define GENS 8
#define NBLOCKS 2048                       // 65536 / (4*8)
#define STRIDE_F 1220                      // LDS row stride (floats), padded
#define STRIDE_F4 305
#define GEN_F4 1200                        // 4 rows * 1200 floats / 4

__global__ __launch_bounds__(256, 4) void fused_chain_kernel(
    const float* __restrict__ input,
    const float* __restrict__ w1g, const float* __restrict__ b1g,
    const float* __restrict__ w2g, const float* __restrict__ b2g,
    const float* __restrict__ w3g, const float* __restrict__ b3g,
    float* __restrict__ feat)
{
    __shared__ __align__(16) float xs[ROWS_PER_GEN * STRIDE_F]; // 19520 B

    const int tid = threadIdx.x;
    const int blk = blockIdx.x;
    const float4* src = (const float4*)(input + (size_t)blk * 32 * 1200);

    float w1[10];
    #pragma unroll
    for (int k = 0; k < 10; ++k) w1[k] = w1g[k];
    const float b1 = b1g[0];
    const float w2a = w2g[0], w2b = w2g[1], w2c = w2g[2], b2 = b2g[0];
    const float w3a = w3g[0], w3b = w3g[1], w3c = w3g[2], w3d = w3g[3];
    const float b3 = b3g[0];

    const int wv = tid >> 6;               // wave 0..3 = row within gen
    const int w  = tid & 63;               // pool1 window (valid < 30)

    // Preload generation 0 into registers.
    float4 pf[5];
    #pragma unroll
    for (int it = 0; it < 5; ++it) {
        const int i = tid + it * 256;
        if (i < GEN_F4) pf[it] = src[i];
    }

    #pragma unroll 1
    for (int g = 0; g < GENS; ++g) {
        // Stage regs -> LDS (coalesced b128 writes).
        #pragma unroll
        for (int it = 0; it < 5; ++it) {
            const int i = tid + it * 256;
            if (i < GEN_F4) {
                const int r = i / 300;
                const int c4 = i - r * 300;
                ((float4*)xs)[r * STRIDE_F4 + c4] = pf[it];
            }
        }
        __syncthreads();

        // Issue next generation's loads; no wait here (first use is the
        // ds_write at the top of the next iteration, after this compute).
        if (g + 1 < GENS) {
            const float4* nsrc = src + (size_t)(g + 1) * GEN_F4;
            #pragma unroll
            for (int it = 0; it < 5; ++it) {
                const int i = tid + it * 256;
                if (i < GEN_F4) pf[it] = nsrc[i];
            }
        }

        // conv1 + pool1: this wave's row, lane w = window.
        float pmax = 0.0f;                 // relu floor folded into pool
        if (w < 30) {
            const float* xr = xs + wv * STRIDE_F + w * 40;
            float v[42];                   // v[m] = x[40w-1+m]
            v[0] = (w == 0) ? 0.0f : xr[-1];
            const float4* xr4 = (const float4*)xr;
            #pragma unroll
            for (int q = 0; q < 10; ++q) {
                const float4 t = xr4[q];
                v[1 + 4 * q] = t.x; v[2 + 4 * q] = t.y;
                v[3 + 4 * q] = t.z; v[4 + 4 * q] = t.w;
            }
            v[41] = (w == 29) ? 0.0f : xr[40];

            #pragma unroll
            for (int i = 0; i < 5; ++i) {
                float acc = b1;
                #pragma unroll
                for (int k = 0; k < 10; ++k) acc = fmaf(w1[k], v[8 * i + k], acc);
                pmax = fmaxf(pmax, acc);
            }
        }

        // conv2 (K=3,s=3): lane j (j<10) computes y2[j] from lanes 3j..3j+2.
        const int jj = (w < 10) ? w : 9;
        const float pa = __shfl(pmax, 3 * jj, 64);
        const float pb = __shfl(pmax, 3 * jj + 1, 64);
        const float pc = __shfl(pmax, 3 * jj + 2, 64);
        const float y2 = fmaxf(fmaf(w2c, pc, fmaf(w2b, pb, fmaf(w2a, pa, b2))), 0.0f);

        // pool2(-inf pad) + conv3 + relu on lane 0.
        const float t1 = __shfl(y2, 1, 64);
        const float t2 = __shfl(y2, 2, 64);
        const float t3 = __shfl(y2, 3, 64);
        const float t4 = __shfl(y2, 4, 64);
        const float t5 = __shfl(y2, 5, 64);
        const float t6 = __shfl(y2, 6, 64);
        const float t7 = __shfl(y2, 7, 64);
        const float t8 = __shfl(y2, 8, 64);
        const float t9 = __shfl(y2, 9, 64);
        if (w == 0) {
            const float q0 = fmaxf(y2, t1);
            const float q1 = fmaxf(fmaxf(t2, t3), t4);
            const float q2 = fmaxf(fmaxf(t5, t6), t7);
            const float q3 = fmaxf(t8, t9);
            float f = b3;
            f = fmaf(w3a, q0, f);
            f = fmaf(w3b, q1, f);
            f = fmaf(w3c, q2, f);
            f = fmaf(w3d, q3, f);
            feat[blk * 32 + g * ROWS_PER_GEN + wv] = fmaxf(f, 0.0f);
        }
        __syncthreads();
    }
}

__global__ __launch_bounds__(256) void classifier_kernel(
    const float* __restrict__ feat,
    const float* __restrict__ cls_w,
    const float* __restrict__ cls_b,
    float* __restrict__ out)
{
    const int b = blockIdx.x;
    const int tid = threadIdx.x;

    float s0 = 0.0f, s1 = 0.0f, s2 = 0.0f;
    for (int n = tid; n < 1024; n += 256) {
        const float f = feat[b * 1024 + n];
        s0 = fmaf(f, cls_w[n], s0);
        s1 = fmaf(f, cls_w[1024 + n], s1);
        s2 = fmaf(f, cls_w[2048 + n], s2);
    }
    #pragma unroll
    for (int off = 32; off > 0; off >>= 1) {
        s0 += __shfl_down(s0, off, 64);
        s1 += __shfl_down(s1, off, 64);
        s2 += __shfl_down(s2, off, 64);
    }
    __shared__ float red[3][4];
    const int wave = tid >> 6;
    if ((tid & 63) == 0) {
        red[0][wave] = s0;
        red[1][wave] = s1;
        red[2][wave] = s2;
    }
    __syncthreads();
    if (tid == 0) {
        const float l0 = red[0][0] + red[0][1] + red[0][2] + red[0][3] + cls_b[0];
        const float l1 = red[1][0] + red[1][1] + red[1][2] + red[1][3] + cls_b[1];
        const float l2 = red[2][0] + red[2][1] + red[2][2] + red[2][3] + cls_b[2];
        const float m = fmaxf(l0, fmaxf(l1, l2));
        const float e0 = expf(l0 - m);
        const float e1 = expf(l1 - m);
        const float e2 = expf(l2 - m);
        const float inv = 1.0f / (e0 + e1 + e2);
        out[b * 3 + 0] = e0 * inv;
        out[b * 3 + 1] = e1 * inv;
        out[b * 3 + 2] = e2 * inv;
    }
}

extern "C" void kernel_launch(void* const* d_in, const int* in_sizes, int n_in,
                              void* d_out, int out_size, void* d_ws, size_t ws_size,
                              hipStream_t stream) {
    const float* input   = (const float*)d_in[0];
    const float* conv1_w = (const float*)d_in[1];
    const float* conv1_b = (const float*)d_in[2];
    const float* conv2_w = (const float*)d_in[3];
    const float* conv2_b = (const float*)d_in[4];
    const float* conv3_w = (const float*)d_in[5];
    const float* conv3_b = (const float*)d_in[6];
    // d_in[7..10]: gcn params — dead code in the reference.
    const float* cls_w   = (const float*)d_in[11];
    const float* cls_b   = (const float*)d_in[12];

    float* featbuf = (float*)d_ws;        // 65536 floats = 256 KB
    float* out     = (float*)d_out;       // 64*3 fp32

    fused_chain_kernel<<<NBLOCKS, 256, 0, stream>>>(
        input, conv1_w, conv1_b, conv2_w, conv2_b, conv3_w, conv3_b, featbuf);
    classifier_kernel<<<64, 256, 0, stream>>>(featbuf, cls_w, cls_b, out);
}